// Round 3
// baseline (598.085 us; speedup 1.0000x reference)
//
#include <hip/hip_runtime.h>
#include <math.h>

#define BSZ 32
#define CH  256

typedef short  bf16x8 __attribute__((ext_vector_type(8)));
typedef float  f32x4  __attribute__((ext_vector_type(4)));
typedef unsigned short ushort_t;
typedef unsigned int   uint_t;

#define MFMA(a, b, c) __builtin_amdgcn_mfma_f32_16x16x32_bf16((a), (b), (c), 0, 0, 0)

__device__ __forceinline__ ushort_t f2b(float f) {
    uint_t u = __builtin_bit_cast(uint_t, f);
    uint_t r = (u + 0x7FFFu + ((u >> 16) & 1u)) >> 16;   // RTNE
    return (ushort_t)r;
}
__device__ __forceinline__ float b2f(ushort_t u) {
    uint_t v = ((uint_t)u) << 16;
    return __builtin_bit_cast(float, v);
}
__device__ __forceinline__ uint_t pk2(float a, float b) {
    return (uint_t)f2b(a) | ((uint_t)f2b(b) << 16);
}

// ---------------- kernel 1: per-cell winning edge (last write wins) -------
__global__ void edge_win_kernel(const int* __restrict__ ei, int E, int nb,
                                int* __restrict__ win) {
    int e = blockIdx.x * blockDim.x + threadIdx.x;
    if (e >= E) return;
    int r = ei[e];
    int c = ei[E + e];
    int br = r >> 5, bc = c >> 5;
    if (br == bc && br < nb) {
        atomicMax(&win[br * (BSZ * BSZ) + (r & 31) * BSZ + (c & 31)], e);
    }
}

// ---------------- kernel 2: fp32 -> bf16 weight conversion ----------------
__global__ void wconv_kernel(const float* __restrict__ qkv_w,
                             const float* __restrict__ proj_w,
                             ushort_t* __restrict__ qkv_wb,
                             ushort_t* __restrict__ proj_wb) {
    int i = blockIdx.x * blockDim.x + threadIdx.x;
    if (i < 768 * 256) qkv_wb[i] = f2b(qkv_w[i]);
    if (i < 256 * 256) proj_wb[i] = f2b(proj_w[i]);
}

// ---------------- kernel 3: qkv GEMM, BM=128 (4 leaf blocks) --------------
// Writes q,k row-major bf16 [row][512] into the d_out buffer (scratch reuse),
// v transposed per leaf block [blk][256][32], and k/v block means (f32).
__global__ __launch_bounds__(256, 2)
void qkv_gemm(const float* __restrict__ x,
              const ushort_t* __restrict__ wb,
              const float* __restrict__ bias,
              ushort_t* __restrict__ qk,
              ushort_t* __restrict__ vT,
              float* __restrict__ krow,
              float* __restrict__ vrow)
{
    __shared__ ushort_t xb[128 * 256];   // 64 KiB, swizzled, 2 blocks/CU
    const int t = threadIdx.x;
    const int wid = t >> 6, lane = t & 63, l15 = lane & 15, lg = lane >> 4;
    const int mbase = blockIdx.x * 128;

    // stage x tile -> bf16 LDS (coalesced 1KB/wave-inst)
    #pragma unroll
    for (int i = 0; i < 32; ++i) {
        int flat = i * 1024 + t * 4;
        int r = flat >> 8, c = flat & 255;
        float4 xv = *(const float4*)&x[(size_t)(mbase + r) * CH + c];
        uint2 w; w.x = pk2(xv.x, xv.y); w.y = pk2(xv.z, xv.w);
        *(uint2*)&xb[r * 256 + (c ^ ((r & 7) << 3))] = w;
    }
    __syncthreads();

    for (int mt = 0; mt < 12; ++mt) {
        int n0 = wid * 192 + mt * 16;
        const ushort_t* arow = wb + (size_t)(n0 + l15) * 256 + lg * 8;
        bf16x8 a[8];
        #pragma unroll
        for (int ks = 0; ks < 8; ++ks) a[ks] = *(const bf16x8*)(arow + ks * 32);
        f32x4 acc[8];
        #pragma unroll
        for (int m = 0; m < 8; ++m) acc[m] = (f32x4){0.f, 0.f, 0.f, 0.f};
        #pragma unroll
        for (int ks = 0; ks < 8; ++ks) {
            int k0 = (ks * 32 + lg * 8) ^ ((l15 & 7) << 3);
            #pragma unroll
            for (int m = 0; m < 8; ++m) {
                bf16x8 bf = *(const bf16x8*)&xb[(m * 16 + l15) * 256 + k0];
                acc[m] = MFMA(a[ks], bf, acc[m]);   // A-frag reused 8x
            }
        }
        f32x4 bv = *(const f32x4*)(bias + n0 + lg * 4);

        if (n0 < 512) {                       // q,k -> row-major [row][512]
            #pragma unroll
            for (int m = 0; m < 8; ++m) {
                f32x4 v = acc[m] + bv;
                uint2 w; w.x = pk2(v[0], v[1]); w.y = pk2(v[2], v[3]);
                int row = mbase + m * 16 + l15;
                *(uint2*)&qk[(size_t)row * 512 + n0 + lg * 4] = w;
            }
        } else {                              // v -> vT[blk][c][r32]
            #pragma unroll
            for (int m = 0; m < 8; ++m) {
                f32x4 v = acc[m] + bv;
                int g = blockIdx.x * 4 + (m >> 1);
                int r32 = (m & 1) * 16 + l15;
                #pragma unroll
                for (int j = 0; j < 4; ++j)
                    vT[(size_t)g * 8192 + (n0 - 512 + lg * 4 + j) * 32 + r32] = f2b(v[j]);
            }
        }
        // k/v block-mean rows via f32 accs + shfl reduce (exact linearity)
        if (n0 >= 256) {
            #pragma unroll
            for (int g = 0; g < 4; ++g) {
                #pragma unroll
                for (int j = 0; j < 4; ++j) {
                    float s = acc[2 * g][j] + acc[2 * g + 1][j];
                    s += __shfl_xor(s, 1);
                    s += __shfl_xor(s, 2);
                    s += __shfl_xor(s, 4);
                    s += __shfl_xor(s, 8);
                    if (l15 == 0) {
                        float val = s * 0.03125f + bv[j];
                        int gb = blockIdx.x * 4 + g;
                        if (n0 < 512) krow[gb * 256 + (n0 - 256) + lg * 4 + j] = val;
                        else          vrow[gb * 256 + (n0 - 512) + lg * 4 + j] = val;
                    }
                }
            }
        }
    }
}

// ---------------- kernel 4: attention + proj per leaf block ---------------
__global__ __launch_bounds__(256, 2)
void leaf_attn(const ushort_t* qk,            // aliases out buffer (bf16 view)
               const ushort_t* __restrict__ vT,
               const float* __restrict__ krow,
               const float* __restrict__ vrow,
               const int*   __restrict__ ei,
               const float* __restrict__ ev,
               const float* __restrict__ pos,
               const ushort_t* __restrict__ proj_wb,
               const float* __restrict__ proj_b,
               const float* __restrict__ gate_w,
               const float* __restrict__ gate_b,
               const int*   __restrict__ win,
               float* out, int E)
{
    __shared__ __align__(16) char smem[79168];
    ushort_t* qb     = (ushort_t*)(smem);           // 16384
    ushort_t* kb     = (ushort_t*)(smem + 16384);   // 16384 -> xo overlay
    ushort_t* xo     = (ushort_t*)(smem + 16384);
    ushort_t* vTl    = (ushort_t*)(smem + 32768);   // 16384
    float*    scf    = (float*)(smem + 49152);      // 128*33*4 = 16896
    ushort_t* comb   = (ushort_t*)(smem + 49152);   // 8192 overlay on scf
    ushort_t* gate4  = (ushort_t*)(smem + 66048);   // 8448
    ushort_t* sbias  = (ushort_t*)(smem + 74496);   // 2112
    float*    krow32 = (float*)(smem + 76608);      // 1024
    float*    vrow32 = (float*)(smem + 77632);      // 1024
    float*    comb32 = (float*)(smem + 78656);      // 512

    const int b = blockIdx.x, t = threadIdx.x;
    const int wid = t >> 6, lane = t & 63, l15 = lane & 15, lg = lane >> 4;
    const int base = b * BSZ;

    // ---- stage q/k (row-major, swizzled) -- coalesced 1KB/wave-inst ------
    #pragma unroll
    for (int i = 0; i < 8; ++i) {
        int cid = i * 256 + t;
        int r = cid >> 6, c8 = (cid & 63) * 8;
        bf16x8 w = *(const bf16x8*)&qk[(size_t)(base + r) * 512 + c8];
        if (c8 < 256) *(bf16x8*)&qb[r * 256 + (c8 ^ ((r & 7) << 3))] = w;
        else          *(bf16x8*)&kb[r * 256 + ((c8 - 256) ^ ((r & 7) << 3))] = w;
    }
    // ---- stage vT (already transposed by K1) -----------------------------
    #pragma unroll
    for (int i = 0; i < 4; ++i) {
        int cid = i * 256 + t;
        int c = cid >> 2, r8 = (cid & 3) * 8;
        bf16x8 w = *(const bf16x8*)&vT[(size_t)b * 8192 + c * 32 + r8];
        *(bf16x8*)&vTl[c * 32 + (r8 ^ ((c & 3) << 3))] = w;
    }
    // ---- stage means -----------------------------------------------------
    krow32[t] = krow[b * 256 + t];
    vrow32[t] = vrow[b * 256 + t];

    // ---- gather: gate4 + sbias -------------------------------------------
    {
        float gwr[16], gbr[4];
        #pragma unroll
        for (int i = 0; i < 16; ++i) gwr[i] = gate_w[i];
        #pragma unroll
        for (int i = 0; i < 4; ++i)  gbr[i] = gate_b[i];
        for (int p = t; p < 32 * 33; p += 256) {
            int qi = p / 33, kj = p - qi * 33;
            float e0 = 0.f, e1 = 0.f, e2 = 0.f, e3 = 0.f;
            bool valid;
            bool fixed = (kj == 32) | (kj == qi);
            if (fixed) { e3 = 1.0f; valid = true; }
            else {
                int w = win[b * 1024 + qi * 32 + kj];
                valid = (w >= 0);
                if (valid) {
                    int rr = ei[w], cc = ei[E + w];
                    e0 = pos[cc * 3 + 0] - pos[rr * 3 + 0];
                    e1 = pos[cc * 3 + 1] - pos[rr * 3 + 1];
                    e2 = pos[cc * 3 + 2] - pos[rr * 3 + 2];
                    e3 = ev[w];
                }
            }
            float sb = valid ? (fixed ? 1.0f : e3) : -INFINITY;
            sbias[p] = f2b(sb);
            #pragma unroll
            for (int h = 0; h < 4; ++h) {
                float g = valid ? (e0 * gwr[h*4+0] + e1 * gwr[h*4+1] +
                                   e2 * gwr[h*4+2] + e3 * gwr[h*4+3] + gbr[h]) : 0.0f;
                gate4[p * 4 + h] = f2b(g);
            }
        }
    }
    __syncthreads();

    // ---- scores MFMA (wave = head), scf layout [(qi*4+h)*33 + kj] --------
    {
        int h = wid;
        const int slQ = (l15 & 7) << 3;
        f32x4 acc00 = {0.f,0.f,0.f,0.f}, acc01 = {0.f,0.f,0.f,0.f};
        f32x4 acc10 = {0.f,0.f,0.f,0.f}, acc11 = {0.f,0.f,0.f,0.f};
        #pragma unroll
        for (int ks = 0; ks < 2; ++ks) {
            int k0 = h * 64 + ks * 32 + lg * 8;
            bf16x8 aq0 = *(const bf16x8*)&qb[l15 * 256 + (k0 ^ slQ)];
            bf16x8 aq1 = *(const bf16x8*)&qb[(16 + l15) * 256 + (k0 ^ slQ)];
            bf16x8 bk0 = *(const bf16x8*)&kb[l15 * 256 + (k0 ^ slQ)];
            bf16x8 bk1 = *(const bf16x8*)&kb[(16 + l15) * 256 + (k0 ^ slQ)];
            acc00 = MFMA(aq0, bk0, acc00);
            acc01 = MFMA(aq0, bk1, acc01);
            acc10 = MFMA(aq1, bk0, acc10);
            acc11 = MFMA(aq1, bk1, acc11);
        }
        #pragma unroll
        for (int j = 0; j < 4; ++j) {
            int qiA = lg * 4 + j, qiB = 16 + lg * 4 + j;
            scf[(qiA * 4 + h) * 33 + l15]      = acc00[j];
            scf[(qiA * 4 + h) * 33 + 16 + l15] = acc01[j];
            scf[(qiB * 4 + h) * 33 + l15]      = acc10[j];
            scf[(qiB * 4 + h) * 33 + 16 + l15] = acc11[j];
        }
    }
    __syncthreads();

    // ---- softmax + gate (128 threads, thread t = row t of scf) -----------
    float rowv[33];
    const int qi5 = t >> 2, h5 = t & 3;
    if (t < 128) {
        #pragma unroll
        for (int kj = 0; kj < 32; ++kj)
            rowv[kj] = scf[t * 33 + kj] * 0.125f + b2f(sbias[qi5 * 33 + kj]);
        float s32 = 0.f;
        const int slQ5 = (qi5 & 7) << 3;
        #pragma unroll
        for (int k = 0; k < 64; ++k)
            s32 += b2f(qb[qi5 * 256 + ((h5 * 64 + k) ^ slQ5)]) * krow32[h5 * 64 + k];
        rowv[32] = s32 * 0.125f + 1.0f;

        float m = rowv[0];
        #pragma unroll
        for (int kj = 1; kj < 33; ++kj) m = fmaxf(m, rowv[kj]);
        float sum = 0.f;
        #pragma unroll
        for (int kj = 0; kj < 33; ++kj) { rowv[kj] = __expf(rowv[kj] - m); sum += rowv[kj]; }
        float inv = 1.0f / sum;
        #pragma unroll
        for (int kj = 0; kj < 33; ++kj)
            rowv[kj] = rowv[kj] * inv + b2f(gate4[(qi5 * 33 + kj) * 4 + h5]);
    }
    __syncthreads();   // scf reads done before comb overwrite
    if (t < 128) {
        #pragma unroll
        for (int kj2 = 0; kj2 < 16; ++kj2)
            ((uint_t*)comb)[(h5 * 32 + qi5) * 16 + (kj2 ^ ((qi5 & 3) << 2))] =
                pk2(rowv[2 * kj2], rowv[2 * kj2 + 1]);
        comb32[h5 * 32 + qi5] = rowv[32];
    }
    __syncthreads();

    // ---- PV MFMA + block-node fixup -> xo (overlays kb) ------------------
    {
        int h = wid;
        const int slC6 = (l15 & 3) << 3;
        #pragma unroll
        for (int ct = 0; ct < 4; ++ct) {
            int cbase = h * 64 + ct * 16;
            bf16x8 a = *(const bf16x8*)&vTl[(cbase + l15) * 32 + ((lg * 8) ^ slC6)];
            #pragma unroll
            for (int qt = 0; qt < 2; ++qt) {
                bf16x8 bfr = *(const bf16x8*)&comb[(h * 32 + qt * 16 + l15) * 32
                                                   + ((lg * 8) ^ slC6)];
                f32x4 acc = {0.f, 0.f, 0.f, 0.f};
                acc = MFMA(a, bfr, acc);
                int qi = qt * 16 + l15;
                float c32 = comb32[h * 32 + qi];
                float r0 = acc[0] + c32 * vrow32[cbase + lg * 4 + 0];
                float r1 = acc[1] + c32 * vrow32[cbase + lg * 4 + 1];
                float r2 = acc[2] + c32 * vrow32[cbase + lg * 4 + 2];
                float r3 = acc[3] + c32 * vrow32[cbase + lg * 4 + 3];
                int c0w = cbase + lg * 4;
                int slR = (l15 & 7) << 3;   // qi&7 == l15&7
                uint2 wv; wv.x = pk2(r0, r1); wv.y = pk2(r2, r3);
                *(uint2*)&xo[qi * 256 + (c0w ^ slR)] = wv;
            }
        }
    }
    __syncthreads();

    // ---- proj MFMA + fp32 global write (overwrites this block's qk rows) -
    {
        const int slR = (l15 & 7) << 3;
        #pragma unroll
        for (int mt = 0; mt < 4; ++mt) {
            int n0 = wid * 64 + mt * 16;
            const ushort_t* arow = proj_wb + (size_t)(n0 + l15) * 256 + lg * 8;
            f32x4 acc0 = {0.f, 0.f, 0.f, 0.f};
            f32x4 acc1 = {0.f, 0.f, 0.f, 0.f};
            #pragma unroll
            for (int ks = 0; ks < 8; ++ks) {
                bf16x8 a  = *(const bf16x8*)(arow + ks * 32);
                int k0 = ks * 32 + lg * 8;
                bf16x8 b0 = *(const bf16x8*)&xo[l15 * 256 + (k0 ^ slR)];
                bf16x8 b1 = *(const bf16x8*)&xo[(16 + l15) * 256 + (k0 ^ slR)];
                acc0 = MFMA(a, b0, acc0);
                acc1 = MFMA(a, b1, acc1);
            }
            f32x4 bv = *(const f32x4*)(proj_b + n0 + lg * 4);
            acc0 += bv; acc1 += bv;
            int c0 = n0 + lg * 4;
            *(f32x4*)(out + (size_t)(base + l15) * 256 + c0)      = acc0;
            *(f32x4*)(out + (size_t)(base + 16 + l15) * 256 + c0) = acc1;
        }
    }
}

extern "C" void kernel_launch(void* const* d_in, const int* in_sizes, int n_in,
                              void* d_out, int out_size, void* d_ws, size_t ws_size,
                              hipStream_t stream) {
    const float* x      = (const float*)d_in[0];
    const int*   ei     = (const int*)  d_in[1];
    const float* ev     = (const float*)d_in[2];
    const float* pos    = (const float*)d_in[3];
    const float* qkv_w  = (const float*)d_in[4];
    const float* qkv_b  = (const float*)d_in[5];
    const float* proj_w = (const float*)d_in[6];
    const float* proj_b = (const float*)d_in[7];
    const float* gate_w = (const float*)d_in[8];
    const float* gate_b = (const float*)d_in[9];
    float* out = (float*)d_out;

    const int E  = in_sizes[2];
    const int N  = in_sizes[0] / CH;
    const int nb = N / BSZ;

    char* ws = (char*)d_ws;
    int* win = (int*)ws;
    size_t off = (size_t)nb * 1024 * 4;                 // 16.8 MB
    ushort_t* qkv_wb  = (ushort_t*)(ws + off); off += 768 * 256 * 2;
    ushort_t* proj_wb = (ushort_t*)(ws + off); off += 256 * 256 * 2;
    float*    krow    = (float*)(ws + off);    off += (size_t)nb * 256 * 4;
    float*    vrow    = (float*)(ws + off);    off += (size_t)nb * 256 * 4;
    ushort_t* vT      = (ushort_t*)(ws + off); off += (size_t)nb * 8192 * 2;
    ushort_t* qk      = (ushort_t*)d_out;               // d_out as bf16 scratch

    hipMemsetAsync(win, 0xFF, (size_t)nb * 1024 * 4, stream);
    edge_win_kernel<<<(E + 255) / 256, 256, 0, stream>>>(ei, E, nb, win);
    wconv_kernel<<<768, 256, 0, stream>>>(qkv_w, proj_w, qkv_wb, proj_wb);
    qkv_gemm<<<nb / 4, 256, 0, stream>>>(x, qkv_wb, qkv_b, qk, vT, krow, vrow);
    leaf_attn<<<nb, 256, 0, stream>>>(qk, vT, krow, vrow, ei, ev, pos,
                                      proj_wb, proj_b, gate_w, gate_b,
                                      win, out, E);
}

// Round 4
// 316.674 us; speedup vs baseline: 1.8886x; 1.8886x over previous
//
#include <hip/hip_runtime.h>
#include <math.h>

#define BSZ 32
#define CH  256

typedef short  bf16x8 __attribute__((ext_vector_type(8)));
typedef float  f32x4  __attribute__((ext_vector_type(4)));
typedef unsigned short ushort_t;
typedef unsigned int   uint_t;

#define MFMA(a, b, c) __builtin_amdgcn_mfma_f32_16x16x32_bf16((a), (b), (c), 0, 0, 0)

__device__ __forceinline__ ushort_t f2b(float f) {
    uint_t u = __builtin_bit_cast(uint_t, f);
    uint_t r = (u + 0x7FFFu + ((u >> 16) & 1u)) >> 16;   // RTNE
    return (ushort_t)r;
}
__device__ __forceinline__ float b2f(ushort_t u) {
    uint_t v = ((uint_t)u) << 16;
    return __builtin_bit_cast(float, v);
}
__device__ __forceinline__ uint_t pk2(float a, float b) {
    return (uint_t)f2b(a) | ((uint_t)f2b(b) << 16);
}
__device__ __forceinline__ bf16x8 u4b8(uint4 u) {
    return __builtin_bit_cast(bf16x8, u);
}

// ---------------- kernel 1: per-cell winning edge (last write wins) -------
__global__ void edge_win_kernel(const int* __restrict__ ei, int E, int nb,
                                int* __restrict__ win) {
    int e = blockIdx.x * blockDim.x + threadIdx.x;
    if (e >= E) return;
    int r = ei[e];
    int c = ei[E + e];
    int br = r >> 5, bc = c >> 5;
    if (br == bc && br < nb) {
        atomicMax(&win[br * (BSZ * BSZ) + (r & 31) * BSZ + (c & 31)], e);
    }
}

// ---------------- kernel 2: fp32 -> bf16 weight conversion ----------------
__global__ void wconv_kernel(const float* __restrict__ qkv_w,
                             const float* __restrict__ proj_w,
                             ushort_t* __restrict__ qkv_wb,
                             ushort_t* __restrict__ proj_wb) {
    int i = blockIdx.x * blockDim.x + threadIdx.x;
    if (i < 768 * 256) qkv_wb[i] = f2b(qkv_w[i]);
    if (i < 256 * 256) proj_wb[i] = f2b(proj_w[i]);
}

// ---------------- kernel 3: qkv GEMM, BM=128 (4 leaf blocks) --------------
// q,k layout (in d_out as bf16): leaf-chunked fragment layout:
//   addr(ushort) = g*16384 + lc*256 + lane*4
//   where g = leaf, lc = tt*2 + (row>>4), tt = ch-tile (q: 0..15, k: 16..31),
//   lane slot (lg=chgrp, l15=row&15) holds 4 ch bf16 {tt*16+lg*4+j, row}.
// v layout: vT[g][ch][32 rows] bf16 (direct transposed store via swapped
//   MFMA orientation). k/v block-means (f32, incl bias) via shfl reduce.
__global__ __launch_bounds__(256, 2)
void qkv_gemm(const float* __restrict__ x,
              const ushort_t* __restrict__ wb,
              const float* __restrict__ bias,
              ushort_t* qk,
              ushort_t* __restrict__ vT,
              float* __restrict__ krow,
              float* __restrict__ vrow)
{
    __shared__ ushort_t xb[128 * 256];   // 64 KiB
    const int t = threadIdx.x;
    const int wid = t >> 6, lane = t & 63, l15 = lane & 15, lg = lane >> 4;
    const int bi = blockIdx.x, mbase = bi * 128;

    // stage x tile -> bf16 LDS (coalesced)
    #pragma unroll 8
    for (int i = 0; i < 32; ++i) {
        int flat = i * 1024 + t * 4;
        int r = flat >> 8, c = flat & 255;
        float4 xv = *(const float4*)&x[(size_t)(mbase + r) * CH + c];
        uint2 w; w.x = pk2(xv.x, xv.y); w.y = pk2(xv.z, xv.w);
        *(uint2*)&xb[r * 256 + (c ^ ((r & 7) << 3))] = w;
    }
    __syncthreads();

    const int slB = (l15 & 7) << 3;
    for (int mt = 0; mt < 12; ++mt) {
        int tt = mt * 4 + wid;               // ch-tile 0..47
        const ushort_t* wrow = wb + (size_t)(tt * 16 + l15) * 256 + lg * 8;
        bf16x8 wf[8];
        #pragma unroll
        for (int ks = 0; ks < 8; ++ks) wf[ks] = *(const bf16x8*)(wrow + ks * 32);
        f32x4 acc[8];
        #pragma unroll
        for (int m = 0; m < 8; ++m) acc[m] = (f32x4){0.f, 0.f, 0.f, 0.f};

        if (tt < 32) {
            // q/k: swapped (A=W rows, B=x rows) -> D[ch][row]
            #pragma unroll
            for (int ks = 0; ks < 8; ++ks) {
                int k0 = (ks * 32 + lg * 8) ^ slB;
                #pragma unroll
                for (int m = 0; m < 8; ++m) {
                    bf16x8 xf = *(const bf16x8*)&xb[(m * 16 + l15) * 256 + k0];
                    acc[m] = MFMA(wf[ks], xf, acc[m]);
                }
            }
            f32x4 bv4 = *(const f32x4*)&bias[tt * 16 + lg * 4];
            #pragma unroll
            for (int m = 0; m < 8; ++m) {
                f32x4 v = acc[m] + bv4;
                uint2 w; w.x = pk2(v[0], v[1]); w.y = pk2(v[2], v[3]);
                int g = bi * 4 + (m >> 1), lc = tt * 2 + (m & 1);
                *(uint2*)&qk[(size_t)g * 16384 + lc * 256 + lane * 4] = w;
            }
            if (tt >= 16) {                  // k block-means
                #pragma unroll
                for (int g = 0; g < 4; ++g) {
                    #pragma unroll
                    for (int j = 0; j < 4; ++j) {
                        float s = acc[2 * g][j] + acc[2 * g + 1][j];
                        s += __shfl_xor(s, 1);
                        s += __shfl_xor(s, 2);
                        s += __shfl_xor(s, 4);
                        s += __shfl_xor(s, 8);
                        if (l15 == 0)
                            krow[(bi * 4 + g) * 256 + (tt - 16) * 16 + lg * 4 + j]
                                = s * 0.03125f + bv4[j];
                    }
                }
            }
        } else {
            // v: non-swapped (A=x rows, B=W rows) -> D[row][ch] (transposed frag)
            #pragma unroll
            for (int ks = 0; ks < 8; ++ks) {
                int k0 = (ks * 32 + lg * 8) ^ slB;
                #pragma unroll
                for (int m = 0; m < 8; ++m) {
                    bf16x8 xf = *(const bf16x8*)&xb[(m * 16 + l15) * 256 + k0];
                    acc[m] = MFMA(xf, wf[ks], acc[m]);
                }
            }
            int vch = (tt - 32) * 16 + l15;
            float bv = bias[512 + vch];
            #pragma unroll
            for (int m = 0; m < 8; ++m) {
                f32x4 v = acc[m];
                uint2 w; w.x = pk2(v[0] + bv, v[1] + bv);
                w.y = pk2(v[2] + bv, v[3] + bv);
                int g = bi * 4 + (m >> 1);
                *(uint2*)&vT[(size_t)g * 8192 + vch * 32 + (m & 1) * 16 + lg * 4] = w;
            }
            #pragma unroll
            for (int g = 0; g < 4; ++g) {    // v block-means
                float s = acc[2*g][0] + acc[2*g][1] + acc[2*g][2] + acc[2*g][3]
                        + acc[2*g+1][0] + acc[2*g+1][1] + acc[2*g+1][2] + acc[2*g+1][3];
                s += __shfl_xor(s, 16);
                s += __shfl_xor(s, 32);
                if (lg == 0)
                    vrow[(bi * 4 + g) * 256 + vch] = s * 0.03125f + bv;
            }
        }
    }
}

// ---------------- kernel 4: attention + proj per leaf block ---------------
// LDS 21,312 B -> 4+ blocks/CU. xo overlays comb/comb32/gate4 (dead by PV).
#define L_COMB   0        // bf16 [4h][32 qi][32 kj swz]          8192 B
#define L_COMB32 8192     // f32 [4h][32 qi]                       512 B
#define L_GATE4  8704     // bf16 [32*33][4h]                     8448 B
#define L_XO     0        // bf16 [32 qi][256 c swz] (overlay)   16384 B
#define L_SBIAS  17152    // bf16 [32*33]                         2112 B
#define L_KROW   19264    // f32 [256]                            1024 B
#define L_VROW   20288    // f32 [256]                            1024 B
#define L_TOTAL  21312

__global__ __launch_bounds__(256, 4)
void leaf_attn(const ushort_t* qk,            // aliases out (bf16 view)
               const ushort_t* __restrict__ vT,
               const float* __restrict__ krow,
               const float* __restrict__ vrow,
               const int*   __restrict__ ei,
               const float* __restrict__ ev,
               const float* __restrict__ pos,
               const ushort_t* __restrict__ proj_wb,
               const float* __restrict__ proj_b,
               const float* __restrict__ gate_w,
               const float* __restrict__ gate_b,
               const int*   __restrict__ win,
               float* out, int E)
{
    __shared__ __align__(16) char smem[L_TOTAL];
    ushort_t* comb   = (ushort_t*)(smem + L_COMB);
    float*    comb32 = (float*)(smem + L_COMB32);
    ushort_t* gate4  = (ushort_t*)(smem + L_GATE4);
    ushort_t* xo     = (ushort_t*)(smem + L_XO);
    ushort_t* sbias  = (ushort_t*)(smem + L_SBIAS);
    float*    krow32 = (float*)(smem + L_KROW);
    float*    vrow32 = (float*)(smem + L_VROW);

    const int b = blockIdx.x, t = threadIdx.x;
    const int h = t >> 6, lane = t & 63, l15 = lane & 15, lg = lane >> 4;
    const int base = b * BSZ;
    const ushort_t* qkb = qk + (size_t)b * 16384;

    // ---- phase A: stage means, direct frag loads, gather ----------------
    krow32[t] = krow[b * 256 + t];
    vrow32[t] = vrow[b * 256 + t];

    uint4 qld[2][2], kld[2][2];              // [row-tile][ks]
    #pragma unroll
    for (int rt = 0; rt < 2; ++rt) {
        #pragma unroll
        for (int ks = 0; ks < 2; ++ks) {
            int ttq = h * 4 + ks * 2 + (lg >> 1);
            int a0 = (ttq * 2 + rt) * 256 + ((lg & 1) * 32 + l15) * 4;
            uint2 u0 = *(const uint2*)&qkb[a0];
            uint2 u1 = *(const uint2*)&qkb[a0 + 64];
            qld[rt][ks] = (uint4){u0.x, u0.y, u1.x, u1.y};
            int b0 = ((ttq + 16) * 2 + rt) * 256 + ((lg & 1) * 32 + l15) * 4;
            uint2 w0 = *(const uint2*)&qkb[b0];
            uint2 w1 = *(const uint2*)&qkb[b0 + 64];
            kld[rt][ks] = (uint4){w0.x, w0.y, w1.x, w1.y};
        }
    }
    bf16x8 vf[4];                            // PV A-frags (vT direct)
    #pragma unroll
    for (int ct = 0; ct < 4; ++ct)
        vf[ct] = *(const bf16x8*)&vT[(size_t)b * 8192
                                     + (h * 64 + ct * 16 + l15) * 32 + lg * 8];

    {   // gather: gate4 + sbias
        float gwr[16], gbr[4];
        #pragma unroll
        for (int i = 0; i < 16; ++i) gwr[i] = gate_w[i];
        #pragma unroll
        for (int i = 0; i < 4; ++i)  gbr[i] = gate_b[i];
        for (int p = t; p < 32 * 33; p += 256) {
            int qi = p / 33, kj = p - qi * 33;
            float e0 = 0.f, e1 = 0.f, e2 = 0.f, e3 = 0.f;
            bool valid;
            bool fixed = (kj == 32) | (kj == qi);
            if (fixed) { e3 = 1.0f; valid = true; }
            else {
                int w = win[b * 1024 + qi * 32 + kj];
                valid = (w >= 0);
                if (valid) {
                    int rr = ei[w], cc = ei[E + w];
                    e0 = pos[cc * 3 + 0] - pos[rr * 3 + 0];
                    e1 = pos[cc * 3 + 1] - pos[rr * 3 + 1];
                    e2 = pos[cc * 3 + 2] - pos[rr * 3 + 2];
                    e3 = ev[w];
                }
            }
            sbias[p] = f2b(valid ? (fixed ? 1.0f : e3) : -INFINITY);
            #pragma unroll
            for (int hh = 0; hh < 4; ++hh) {
                float g = valid ? (e0 * gwr[hh*4+0] + e1 * gwr[hh*4+1] +
                                   e2 * gwr[hh*4+2] + e3 * gwr[hh*4+3] + gbr[hh]) : 0.0f;
                gate4[p * 4 + hh] = f2b(g);
            }
        }
    }
    __syncthreads();

    // ---- scores MFMA: A=k (M=kj), B=q (N=qi) -> D[kj][qi] ---------------
    bf16x8 kr2[2];
    #pragma unroll
    for (int ks = 0; ks < 2; ++ks) {
        uint4 u = {0u, 0u, 0u, 0u};
        if (l15 == 0) {
            const float* kp = &krow32[h * 64 + ks * 32 + lg * 8];
            u.x = pk2(kp[0], kp[1]); u.y = pk2(kp[2], kp[3]);
            u.z = pk2(kp[4], kp[5]); u.w = pk2(kp[6], kp[7]);
        }
        kr2[ks] = u4b8(u);
    }
    f32x4 s[2][2], s2[2];
    #pragma unroll
    for (int qt = 0; qt < 2; ++qt) {
        s[qt][0] = (f32x4){0.f,0.f,0.f,0.f};
        s[qt][1] = (f32x4){0.f,0.f,0.f,0.f};
        s2[qt]   = (f32x4){0.f,0.f,0.f,0.f};
    }
    #pragma unroll
    for (int qt = 0; qt < 2; ++qt) {
        #pragma unroll
        for (int ks = 0; ks < 2; ++ks) {
            bf16x8 qf = u4b8(qld[qt][ks]);
            #pragma unroll
            for (int kt = 0; kt < 2; ++kt)
                s[qt][kt] = MFMA(u4b8(kld[kt][ks]), qf, s[qt][kt]);
            s2[qt] = MFMA(kr2[ks], qf, s2[qt]);
        }
    }

    // ---- softmax + gate (in-register; row qi lives on lane column l15) --
    #pragma unroll
    for (int qt = 0; qt < 2; ++qt) {
        int qi = qt * 16 + l15;
        float r[8];
        #pragma unroll
        for (int kt = 0; kt < 2; ++kt)
            #pragma unroll
            for (int j = 0; j < 4; ++j)
                r[kt * 4 + j] = s[qt][kt][j] * 0.125f
                              + b2f(sbias[qi * 33 + kt * 16 + lg * 4 + j]);
        float r2 = s2[qt][0] * 0.125f + 1.0f;      // valid on lg==0 (kj=32)
        float m = fmaxf(fmaxf(fmaxf(r[0], r[1]), fmaxf(r[2], r[3])),
                        fmaxf(fmaxf(r[4], r[5]), fmaxf(r[6], r[7])));
        if (lg == 0) m = fmaxf(m, r2);
        m = fmaxf(m, __shfl_xor(m, 16));
        m = fmaxf(m, __shfl_xor(m, 32));
        float sum = 0.f;
        #pragma unroll
        for (int i = 0; i < 8; ++i) { r[i] = __expf(r[i] - m); sum += r[i]; }
        float e2 = (lg == 0) ? __expf(r2 - m) : 0.f;
        sum += e2;
        sum += __shfl_xor(sum, 16);
        sum += __shfl_xor(sum, 32);
        float inv = 1.0f / sum;
        int swz = (l15 >> 2) << 3;                 // ((qi>>2)&3)<<3
        #pragma unroll
        for (int kt = 0; kt < 2; ++kt) {
            int kj0 = kt * 16 + lg * 4;
            uint2 w;
            w.x = pk2(r[kt*4+0] * inv + b2f(gate4[(qi * 33 + kj0 + 0) * 4 + h]),
                      r[kt*4+1] * inv + b2f(gate4[(qi * 33 + kj0 + 1) * 4 + h]));
            w.y = pk2(r[kt*4+2] * inv + b2f(gate4[(qi * 33 + kj0 + 2) * 4 + h]),
                      r[kt*4+3] * inv + b2f(gate4[(qi * 33 + kj0 + 3) * 4 + h]));
            *(uint2*)&comb[(h * 32 + qi) * 32 + (kj0 ^ swz)] = w;
        }
        if (lg == 0)
            comb32[h * 32 + qi] = e2 * inv + b2f(gate4[(qi * 33 + 32) * 4 + h]);
    }
    __syncthreads();

    // ---- PV: pre-read comb frags to regs (xo overlay safety) ------------
    bf16x8 cfr[2];
    float c32[2];
    #pragma unroll
    for (int qt = 0; qt < 2; ++qt) {
        int qi = qt * 16 + l15;
        int off = (lg * 8) ^ (((l15 >> 2) & 3) << 3);
        cfr[qt] = *(const bf16x8*)&comb[(h * 32 + qi) * 32 + off];
        c32[qt] = comb32[h * 32 + qi];
    }
    f32x4 vr[4];
    #pragma unroll
    for (int ct = 0; ct < 4; ++ct)
        vr[ct] = *(const f32x4*)&vrow32[h * 64 + ct * 16 + lg * 4];
    __syncthreads();

    // ---- PV MFMA: A=vT (M=c), B=comb (N=qi) -> D[c][qi] + fixup ---------
    #pragma unroll
    for (int ct = 0; ct < 4; ++ct) {
        #pragma unroll
        for (int qt = 0; qt < 2; ++qt) {
            f32x4 acc = {0.f, 0.f, 0.f, 0.f};
            acc = MFMA(vf[ct], cfr[qt], acc);
            int qi = qt * 16 + l15;
            float c2 = c32[qt];
            uint2 w;
            w.x = pk2(acc[0] + c2 * vr[ct][0], acc[1] + c2 * vr[ct][1]);
            w.y = pk2(acc[2] + c2 * vr[ct][2], acc[3] + c2 * vr[ct][3]);
            int c0 = h * 64 + ct * 16 + lg * 4;
            *(uint2*)&xo[qi * 256 + (c0 ^ ((l15 & 7) << 3))] = w;
        }
    }
    __syncthreads();

    // ---- proj MFMA (swapped) + fp32 out store ---------------------------
    {
        const int slR = (l15 & 7) << 3;
        #pragma unroll
        for (int mt = 0; mt < 4; ++mt) {
            int n0 = h * 64 + mt * 16;
            const ushort_t* arow = proj_wb + (size_t)(n0 + l15) * 256 + lg * 8;
            f32x4 acc0 = {0.f, 0.f, 0.f, 0.f};
            f32x4 acc1 = {0.f, 0.f, 0.f, 0.f};
            #pragma unroll
            for (int ks = 0; ks < 8; ++ks) {
                bf16x8 a  = *(const bf16x8*)(arow + ks * 32);
                int k0 = ks * 32 + lg * 8;
                bf16x8 b0 = *(const bf16x8*)&xo[l15 * 256 + (k0 ^ slR)];
                bf16x8 b1 = *(const bf16x8*)&xo[(16 + l15) * 256 + (k0 ^ slR)];
                acc0 = MFMA(a, b0, acc0);
                acc1 = MFMA(a, b1, acc1);
            }
            f32x4 bv = *(const f32x4*)(proj_b + n0 + lg * 4);
            acc0 += bv; acc1 += bv;
            int c0 = n0 + lg * 4;
            *(f32x4*)(out + (size_t)(base + l15) * 256 + c0)      = acc0;
            *(f32x4*)(out + (size_t)(base + 16 + l15) * 256 + c0) = acc1;
        }
    }
}

extern "C" void kernel_launch(void* const* d_in, const int* in_sizes, int n_in,
                              void* d_out, int out_size, void* d_ws, size_t ws_size,
                              hipStream_t stream) {
    const float* x      = (const float*)d_in[0];
    const int*   ei     = (const int*)  d_in[1];
    const float* ev     = (const float*)d_in[2];
    const float* pos    = (const float*)d_in[3];
    const float* qkv_w  = (const float*)d_in[4];
    const float* qkv_b  = (const float*)d_in[5];
    const float* proj_w = (const float*)d_in[6];
    const float* proj_b = (const float*)d_in[7];
    const float* gate_w = (const float*)d_in[8];
    const float* gate_b = (const float*)d_in[9];
    float* out = (float*)d_out;

    const int E  = in_sizes[2];
    const int N  = in_sizes[0] / CH;
    const int nb = N / BSZ;

    char* ws = (char*)d_ws;
    int* win = (int*)ws;
    size_t off = (size_t)nb * 1024 * 4;                 // 16.8 MB
    ushort_t* qkv_wb  = (ushort_t*)(ws + off); off += 768 * 256 * 2;
    ushort_t* proj_wb = (ushort_t*)(ws + off); off += 256 * 256 * 2;
    float*    krow    = (float*)(ws + off);    off += (size_t)nb * 256 * 4;
    float*    vrow    = (float*)(ws + off);    off += (size_t)nb * 256 * 4;
    ushort_t* vT      = (ushort_t*)(ws + off); off += (size_t)nb * 8192 * 2;
    ushort_t* qk      = (ushort_t*)d_out;               // d_out as bf16 scratch

    hipMemsetAsync(win, 0xFF, (size_t)nb * 1024 * 4, stream);
    edge_win_kernel<<<(E + 255) / 256, 256, 0, stream>>>(ei, E, nb, win);
    wconv_kernel<<<768, 256, 0, stream>>>(qkv_w, proj_w, qkv_wb, proj_wb);
    qkv_gemm<<<nb / 4, 256, 0, stream>>>(x, qkv_wb, qkv_b, qk, vT, krow, vrow);
    leaf_attn<<<nb, 256, 0, stream>>>(qk, vT, krow, vrow, ei, ev, pos,
                                      proj_wb, proj_b, gate_w, gate_b,
                                      win, out, E);
}